// Round 2
// baseline (424.706 us; speedup 1.0000x reference)
//
#include <hip/hip_runtime.h>

// WassersteinLoss: per-row W1 = (1/N) * sum_i |sort(u)[i] - sort(v)[i]|, mean over rows.
// R6: occupancy fix. R5 post-mortem: VALU-busy product fell 38% (prediction met)
//   but time only -19%; VALUBusy 89->68, Occupancy 38%. LDS 34.3 KB/block caps
//   residency at 4 blocks/CU (16/32 waves) -> latency exposed, no pipe saturated.
//   Change: wave-role-split t^127 exchange -> only upper waves (t&64) stage their
//   32 regs in LDS (128x33 floats = 16.9 KB, half of R5). Lower waves read the
//   mirror partner value, compute min (keep) AND max (write back); uppers re-read.
//   Whole-wave-uniform branches (waves 1,3 vs 0,2), same DS op count, +1 barrier.
//   -> 8 blocks/CU resident (launch_bounds(256,8), VGPR 52 <= 64), single round.
// R5 carried forward: ascending-only mirror bitonic (no sign-negation), 2-VALU
//   compare-select ce2, DPP for m=1,2 / bperm for m>=4 exchanges.

constexpr int N_ELEM  = 4096;
constexpr int V       = 32;     // elements per thread per array
constexpr int THREADS = 256;    // 4 waves = 2 rows per block

// ---- compare-select: keep min(x,o) if keep_min, else max(x,o).
//      ((o<x) != keep_min) ? x : o  — v_cmp + s_xor_b64 (SALU) + v_cndmask.
__device__ __forceinline__ float ce2(float x, float o, bool keep_min) {
    return ((o < x) != keep_min) ? x : o;
}

// ---- in-register ascending merge of S-blocks: mirror + descend S/4..1 ----
template<int S>
__device__ __forceinline__ void reg_merge(float r[V]) {
    #pragma unroll
    for (int k = 0; k < V; ++k) {
        if ((k & (S >> 1)) == 0) {
            const int j = k ^ (S - 1);          // complement low bits = mirror partner
            const float a = r[k], b = r[j];
            r[k] = fminf(a, b);
            r[j] = fmaxf(a, b);
        }
    }
    #pragma unroll
    for (int s = S >> 2; s >= 1; s >>= 1) {
        #pragma unroll
        for (int k = 0; k < V; ++k) {
            if ((k & s) == 0) {
                const float a = r[k], b = r[k + s];
                r[k]     = fminf(a, b);
                r[k + s] = fmaxf(a, b);
            }
        }
    }
}

// ---- ascending register descend, strides 16..1 (tail of every cross stage) ----
__device__ __forceinline__ void reg_tail_asc(float r[V]) {
    #pragma unroll
    for (int s = 16; s >= 1; s >>= 1) {
        #pragma unroll
        for (int k = 0; k < V; ++k) {
            if ((k & s) == 0) {
                const float a = r[k], b = r[k + s];
                r[k]     = fminf(a, b);
                r[k + s] = fmaxf(a, b);
            }
        }
    }
}

template<int CTRL>
__device__ __forceinline__ float dpp_x(float x) {
    return __int_as_float(__builtin_amdgcn_mov_dpp(__float_as_int(x), CTRL, 0xF, 0xF, true));
}
__device__ __forceinline__ float bperm_x(int pa, float x) {
    return __int_as_float(__builtin_amdgcn_ds_bpermute(pa, __float_as_int(x)));
}

// ---- descend xor pass, lane partner lane^M, keep_min at (lane&M)==0 ----
template<int M>
__device__ __forceinline__ void xor_pass(float ru[V], float rv[V], int lane) {
    const bool keep_min = (lane & M) == 0;
    if constexpr (M == 1) {
        #pragma unroll
        for (int k = 0; k < V; ++k) {
            ru[k] = ce2(ru[k], dpp_x<0xB1>(ru[k]), keep_min);
            rv[k] = ce2(rv[k], dpp_x<0xB1>(rv[k]), keep_min);
        }
    } else if constexpr (M == 2) {
        #pragma unroll
        for (int k = 0; k < V; ++k) {
            ru[k] = ce2(ru[k], dpp_x<0x4E>(ru[k]), keep_min);
            rv[k] = ce2(rv[k], dpp_x<0x4E>(rv[k]), keep_min);
        }
    } else {
        const int pa = (lane ^ M) << 2;
        #pragma unroll
        for (int k = 0; k < V; ++k) {
            ru[k] = ce2(ru[k], bperm_x(pa, ru[k]), keep_min);
            rv[k] = ce2(rv[k], bperm_x(pa, rv[k]), keep_min);
        }
    }
}

// ---- cross descend m=MMAX..1 then register tail (strides 16..1) ----
template<int MMAX>
__device__ __forceinline__ void cross_descend(float ru[V], float rv[V], int lane) {
    if constexpr (MMAX >= 32) xor_pass<32>(ru, rv, lane);
    if constexpr (MMAX >= 16) xor_pass<16>(ru, rv, lane);
    if constexpr (MMAX >= 8)  xor_pass<8>(ru, rv, lane);
    if constexpr (MMAX >= 4)  xor_pass<4>(ru, rv, lane);
    if constexpr (MMAX >= 2)  xor_pass<2>(ru, rv, lane);
    if constexpr (MMAX >= 1)  xor_pass<1>(ru, rv, lane);
    reg_tail_asc(ru);
    reg_tail_asc(rv);
}

// ---- cross mirror pass: (t,k) <-> (t^X, 31-k); keep_min at (t & (X+1)/2)==0.
//      Pairs (k, 31-k) handled jointly so reads precede writes (no hazard). ----
template<int X>
__device__ __forceinline__ void mirror_pass(float ru[V], float rv[V], int lane) {
    const bool keep_min = (lane & ((X + 1) >> 1)) == 0;
    if constexpr (X == 1) {
        #pragma unroll
        for (int k = 0; k < V / 2; ++k) {
            const int j = V - 1 - k;
            const float ua = dpp_x<0xB1>(ru[j]);
            const float ub = dpp_x<0xB1>(ru[k]);
            ru[k] = ce2(ru[k], ua, keep_min);
            ru[j] = ce2(ru[j], ub, keep_min);
            const float va = dpp_x<0xB1>(rv[j]);
            const float vb = dpp_x<0xB1>(rv[k]);
            rv[k] = ce2(rv[k], va, keep_min);
            rv[j] = ce2(rv[j], vb, keep_min);
        }
    } else {
        const int pa = (lane ^ X) << 2;
        #pragma unroll
        for (int k = 0; k < V / 2; ++k) {
            const int j = V - 1 - k;
            const float ua = bperm_x(pa, ru[j]);
            const float ub = bperm_x(pa, ru[k]);
            ru[k] = ce2(ru[k], ua, keep_min);
            ru[j] = ce2(ru[j], ub, keep_min);
            const float va = bperm_x(pa, rv[j]);
            const float vb = bperm_x(pa, rv[k]);
            rv[k] = ce2(rv[k], va, keep_min);
            rv[j] = ce2(rv[j], vb, keep_min);
        }
    }
}

// ---- full merge stage S (64..2048): cross mirror + cross descend + reg tail ----
template<int S>
__device__ __forceinline__ void stage_m(float ru[V], float rv[V], int lane) {
    mirror_pass<(S >> 5) - 1>(ru, rv, lane);   // X = S/32 - 1  (t-bit mirror mask)
    cross_descend<(S >> 7)>(ru, rv, lane);     // descend strides S/4..32 -> m = S/128..1
}

__global__ __launch_bounds__(THREADS, 8) void w1_rows_kernel(
    const float* __restrict__ pred,
    const float* __restrict__ tru,
    float* __restrict__ out,
    float scale)
{
    // Staging for UPPER threads only (t&64): 128 slots x stride 33 = 16896 B.
    __shared__ float xbuf[128 * 33];
    __shared__ float wsum[THREADS / 64];

    const int tid  = threadIdx.x;
    const int t    = tid & 127;            // thread index within the row (0..127)
    const int lane = tid & 63;
    const int row  = blockIdx.x * 2 + (tid >> 7);
    const size_t base = (size_t)row * N_ELEM + (size_t)t * V;

    // Blocked layout: row-thread t owns global indices [32t, 32t+32).
    float ru[V], rv[V];
    {
        const float4* u4 = (const float4*)(pred + base);
        const float4* v4 = (const float4*)(tru  + base);
        #pragma unroll
        for (int c = 0; c < V / 4; ++c) {
            float4 a = u4[c], b = v4[c];
            ru[4*c+0] = a.x; ru[4*c+1] = a.y; ru[4*c+2] = a.z; ru[4*c+3] = a.w;
            rv[4*c+0] = b.x; rv[4*c+1] = b.y; rv[4*c+2] = b.z; rv[4*c+3] = b.w;
        }
    }

    // Stages S=2..32: fully in-register ascending sort of each 32-run.
    reg_merge<2>(ru);  reg_merge<2>(rv);
    reg_merge<4>(ru);  reg_merge<4>(rv);
    reg_merge<8>(ru);  reg_merge<8>(rv);
    reg_merge<16>(ru); reg_merge<16>(rv);
    reg_merge<32>(ru); reg_merge<32>(rv);

    // Stages S=64..2048: cross-lane mirror + descend, everything ascending.
    stage_m<64>(ru, rv, lane);
    stage_m<128>(ru, rv, lane);
    stage_m<256>(ru, rv, lane);
    stage_m<512>(ru, rv, lane);
    stage_m<1024>(ru, rv, lane);
    stage_m<2048>(ru, rv, lane);

    // Stage S=4096: mirror pass g <-> g^4095, i.e. (t,k) <-> (t^127, 31-k).
    // Wave-role split: uppers (t&64, waves 1&3 of the block) stage all 32 regs;
    // lowers read partner value reversed (slot 63-lane, elem 31-k), keep min,
    // write max back; uppers re-read. Whole-wave-uniform branches.
    {
        const bool is_upper = (t & 64) != 0;
        const int  slot_row = (tid >> 7) * 64;
        const int  my_base  = (slot_row + lane) * 33;        // uppers' own slot
        const int  pa_base  = (slot_row + (63 - lane)) * 33; // lowers' partner slot

        // ---- array u ----
        if (is_upper) {
            #pragma unroll
            for (int k = 0; k < V; ++k) xbuf[my_base + k] = ru[k];
        }
        __syncthreads();
        if (!is_upper) {
            #pragma unroll
            for (int k = 0; k < V; ++k) {
                const int  e = V - 1 - k;
                const float o  = xbuf[pa_base + e];
                const float mx = fmaxf(ru[k], o);
                ru[k] = fminf(ru[k], o);          // lower keeps min
                xbuf[pa_base + e] = mx;           // partner's result
            }
        }
        __syncthreads();
        if (is_upper) {
            #pragma unroll
            for (int k = 0; k < V; ++k) ru[k] = xbuf[my_base + k];
        }

        // ---- array v ---- (uppers' own-slot read->write is program-ordered)
        if (is_upper) {
            #pragma unroll
            for (int k = 0; k < V; ++k) xbuf[my_base + k] = rv[k];
        }
        __syncthreads();
        if (!is_upper) {
            #pragma unroll
            for (int k = 0; k < V; ++k) {
                const int  e = V - 1 - k;
                const float o  = xbuf[pa_base + e];
                const float mx = fmaxf(rv[k], o);
                rv[k] = fminf(rv[k], o);
                xbuf[pa_base + e] = mx;
            }
        }
        __syncthreads();
        if (is_upper) {
            #pragma unroll
            for (int k = 0; k < V; ++k) rv[k] = xbuf[my_base + k];
        }

        cross_descend<32>(ru, rv, lane);       // strides 1024..32 then reg tail
    }

    // Epilogue: per-thread |diff| sum, wave reduce, block reduce, one atomic.
    float part = 0.f;
    #pragma unroll
    for (int k = 0; k < V; ++k) part += fabsf(ru[k] - rv[k]);

    #pragma unroll
    for (int off = 32; off > 0; off >>= 1)
        part += __shfl_down(part, off, 64);

    const int wid = tid >> 6;
    if (lane == 0) wsum[wid] = part;
    __syncthreads();
    if (tid == 0) {
        float tot = wsum[0] + wsum[1] + wsum[2] + wsum[3];
        atomicAdd(out, tot * scale);
    }
}

extern "C" void kernel_launch(void* const* d_in, const int* in_sizes, int n_in,
                              void* d_out, int out_size, void* d_ws, size_t ws_size,
                              hipStream_t stream)
{
    (void)n_in; (void)out_size; (void)d_ws; (void)ws_size;

    const float* pred = (const float*)d_in[0];
    const float* tru  = (const float*)d_in[1];
    float* out = (float*)d_out;

    const int B = in_sizes[0] / N_ELEM;   // 4096 rows

    hipMemsetAsync(out, 0, sizeof(float), stream);

    const float scale = 1.0f / ((float)N_ELEM * (float)B);
    w1_rows_kernel<<<B / 2, THREADS, 0, stream>>>(pred, tru, out, scale);
}

// Round 3
// 253.351 us; speedup vs baseline: 1.6764x; 1.6764x over previous
//
#include <hip/hip_runtime.h>

// WassersteinLoss: per-row W1 = (1/N) * sum_i |sort(u)[i] - sort(v)[i]|, mean over rows.
// R7: fix R6's spill. R6 post-mortem: launch_bounds(256,8) = 64-reg cap < the
//   64-reg ru/rv working set -> compiler spilled the sort arrays to scratch
//   (WRITE_SIZE 64KB -> 896MB, FETCH 66MB -> 458MB, 2x slowdown). The LDS
//   halving itself worked (17408 B, conflicts 0).
//   Change: launch_bounds(256,5) -> 102-reg cap. Fits ~90-reg true pressure
//   (64 array + temps), allows 5 waves/SIMD (20 waves/CU, vs R5's 16 at 4
//   blocks LDS-limited). LDS no longer binds (9 blocks would fit).
//   Spill tripwire: if WRITE_SIZE >> 64 KB again, revert to bounds=4.
// Carried: ascending-only mirror bitonic, 2-VALU ce2, DPP m=1,2 / bperm m>=4,
//   wave-role-split t^127 LDS exchange (uppers stage, lowers min/max+writeback).

constexpr int N_ELEM  = 4096;
constexpr int V       = 32;     // elements per thread per array
constexpr int THREADS = 256;    // 4 waves = 2 rows per block

// ---- compare-select: keep min(x,o) if keep_min, else max(x,o).
//      ((o<x) != keep_min) ? x : o  — v_cmp + s_xor_b64 (SALU) + v_cndmask.
__device__ __forceinline__ float ce2(float x, float o, bool keep_min) {
    return ((o < x) != keep_min) ? x : o;
}

// ---- in-register ascending merge of S-blocks: mirror + descend S/4..1 ----
template<int S>
__device__ __forceinline__ void reg_merge(float r[V]) {
    #pragma unroll
    for (int k = 0; k < V; ++k) {
        if ((k & (S >> 1)) == 0) {
            const int j = k ^ (S - 1);          // complement low bits = mirror partner
            const float a = r[k], b = r[j];
            r[k] = fminf(a, b);
            r[j] = fmaxf(a, b);
        }
    }
    #pragma unroll
    for (int s = S >> 2; s >= 1; s >>= 1) {
        #pragma unroll
        for (int k = 0; k < V; ++k) {
            if ((k & s) == 0) {
                const float a = r[k], b = r[k + s];
                r[k]     = fminf(a, b);
                r[k + s] = fmaxf(a, b);
            }
        }
    }
}

// ---- ascending register descend, strides 16..1 (tail of every cross stage) ----
__device__ __forceinline__ void reg_tail_asc(float r[V]) {
    #pragma unroll
    for (int s = 16; s >= 1; s >>= 1) {
        #pragma unroll
        for (int k = 0; k < V; ++k) {
            if ((k & s) == 0) {
                const float a = r[k], b = r[k + s];
                r[k]     = fminf(a, b);
                r[k + s] = fmaxf(a, b);
            }
        }
    }
}

template<int CTRL>
__device__ __forceinline__ float dpp_x(float x) {
    return __int_as_float(__builtin_amdgcn_mov_dpp(__float_as_int(x), CTRL, 0xF, 0xF, true));
}
__device__ __forceinline__ float bperm_x(int pa, float x) {
    return __int_as_float(__builtin_amdgcn_ds_bpermute(pa, __float_as_int(x)));
}

// ---- descend xor pass, lane partner lane^M, keep_min at (lane&M)==0 ----
template<int M>
__device__ __forceinline__ void xor_pass(float ru[V], float rv[V], int lane) {
    const bool keep_min = (lane & M) == 0;
    if constexpr (M == 1) {
        #pragma unroll
        for (int k = 0; k < V; ++k) {
            ru[k] = ce2(ru[k], dpp_x<0xB1>(ru[k]), keep_min);
            rv[k] = ce2(rv[k], dpp_x<0xB1>(rv[k]), keep_min);
        }
    } else if constexpr (M == 2) {
        #pragma unroll
        for (int k = 0; k < V; ++k) {
            ru[k] = ce2(ru[k], dpp_x<0x4E>(ru[k]), keep_min);
            rv[k] = ce2(rv[k], dpp_x<0x4E>(rv[k]), keep_min);
        }
    } else {
        const int pa = (lane ^ M) << 2;
        #pragma unroll
        for (int k = 0; k < V; ++k) {
            ru[k] = ce2(ru[k], bperm_x(pa, ru[k]), keep_min);
            rv[k] = ce2(rv[k], bperm_x(pa, rv[k]), keep_min);
        }
    }
}

// ---- cross descend m=MMAX..1 then register tail (strides 16..1) ----
template<int MMAX>
__device__ __forceinline__ void cross_descend(float ru[V], float rv[V], int lane) {
    if constexpr (MMAX >= 32) xor_pass<32>(ru, rv, lane);
    if constexpr (MMAX >= 16) xor_pass<16>(ru, rv, lane);
    if constexpr (MMAX >= 8)  xor_pass<8>(ru, rv, lane);
    if constexpr (MMAX >= 4)  xor_pass<4>(ru, rv, lane);
    if constexpr (MMAX >= 2)  xor_pass<2>(ru, rv, lane);
    if constexpr (MMAX >= 1)  xor_pass<1>(ru, rv, lane);
    reg_tail_asc(ru);
    reg_tail_asc(rv);
}

// ---- cross mirror pass: (t,k) <-> (t^X, 31-k); keep_min at (t & (X+1)/2)==0.
//      Pairs (k, 31-k) handled jointly so reads precede writes (no hazard). ----
template<int X>
__device__ __forceinline__ void mirror_pass(float ru[V], float rv[V], int lane) {
    const bool keep_min = (lane & ((X + 1) >> 1)) == 0;
    if constexpr (X == 1) {
        #pragma unroll
        for (int k = 0; k < V / 2; ++k) {
            const int j = V - 1 - k;
            const float ua = dpp_x<0xB1>(ru[j]);
            const float ub = dpp_x<0xB1>(ru[k]);
            ru[k] = ce2(ru[k], ua, keep_min);
            ru[j] = ce2(ru[j], ub, keep_min);
            const float va = dpp_x<0xB1>(rv[j]);
            const float vb = dpp_x<0xB1>(rv[k]);
            rv[k] = ce2(rv[k], va, keep_min);
            rv[j] = ce2(rv[j], vb, keep_min);
        }
    } else {
        const int pa = (lane ^ X) << 2;
        #pragma unroll
        for (int k = 0; k < V / 2; ++k) {
            const int j = V - 1 - k;
            const float ua = bperm_x(pa, ru[j]);
            const float ub = bperm_x(pa, ru[k]);
            ru[k] = ce2(ru[k], ua, keep_min);
            ru[j] = ce2(ru[j], ub, keep_min);
            const float va = bperm_x(pa, rv[j]);
            const float vb = bperm_x(pa, rv[k]);
            rv[k] = ce2(rv[k], va, keep_min);
            rv[j] = ce2(rv[j], vb, keep_min);
        }
    }
}

// ---- full merge stage S (64..2048): cross mirror + cross descend + reg tail ----
template<int S>
__device__ __forceinline__ void stage_m(float ru[V], float rv[V], int lane) {
    mirror_pass<(S >> 5) - 1>(ru, rv, lane);   // X = S/32 - 1  (t-bit mirror mask)
    cross_descend<(S >> 7)>(ru, rv, lane);     // descend strides S/4..32 -> m = S/128..1
}

__global__ __launch_bounds__(THREADS, 5) void w1_rows_kernel(
    const float* __restrict__ pred,
    const float* __restrict__ tru,
    float* __restrict__ out,
    float scale)
{
    // Staging for UPPER threads only (t&64): 128 slots x stride 33 = 16896 B.
    __shared__ float xbuf[128 * 33];
    __shared__ float wsum[THREADS / 64];

    const int tid  = threadIdx.x;
    const int t    = tid & 127;            // thread index within the row (0..127)
    const int lane = tid & 63;
    const int row  = blockIdx.x * 2 + (tid >> 7);
    const size_t base = (size_t)row * N_ELEM + (size_t)t * V;

    // Blocked layout: row-thread t owns global indices [32t, 32t+32).
    float ru[V], rv[V];
    {
        const float4* u4 = (const float4*)(pred + base);
        const float4* v4 = (const float4*)(tru  + base);
        #pragma unroll
        for (int c = 0; c < V / 4; ++c) {
            float4 a = u4[c], b = v4[c];
            ru[4*c+0] = a.x; ru[4*c+1] = a.y; ru[4*c+2] = a.z; ru[4*c+3] = a.w;
            rv[4*c+0] = b.x; rv[4*c+1] = b.y; rv[4*c+2] = b.z; rv[4*c+3] = b.w;
        }
    }

    // Stages S=2..32: fully in-register ascending sort of each 32-run.
    reg_merge<2>(ru);  reg_merge<2>(rv);
    reg_merge<4>(ru);  reg_merge<4>(rv);
    reg_merge<8>(ru);  reg_merge<8>(rv);
    reg_merge<16>(ru); reg_merge<16>(rv);
    reg_merge<32>(ru); reg_merge<32>(rv);

    // Stages S=64..2048: cross-lane mirror + descend, everything ascending.
    stage_m<64>(ru, rv, lane);
    stage_m<128>(ru, rv, lane);
    stage_m<256>(ru, rv, lane);
    stage_m<512>(ru, rv, lane);
    stage_m<1024>(ru, rv, lane);
    stage_m<2048>(ru, rv, lane);

    // Stage S=4096: mirror pass g <-> g^4095, i.e. (t,k) <-> (t^127, 31-k).
    // Wave-role split: uppers (t&64, waves 1&3 of the block) stage all 32 regs;
    // lowers read partner value reversed (slot 63-lane, elem 31-k), keep min,
    // write max back; uppers re-read. Whole-wave-uniform branches.
    {
        const bool is_upper = (t & 64) != 0;
        const int  slot_row = (tid >> 7) * 64;
        const int  my_base  = (slot_row + lane) * 33;        // uppers' own slot
        const int  pa_base  = (slot_row + (63 - lane)) * 33; // lowers' partner slot

        // ---- array u ----
        if (is_upper) {
            #pragma unroll
            for (int k = 0; k < V; ++k) xbuf[my_base + k] = ru[k];
        }
        __syncthreads();
        if (!is_upper) {
            #pragma unroll
            for (int k = 0; k < V; ++k) {
                const int  e = V - 1 - k;
                const float o  = xbuf[pa_base + e];
                const float mx = fmaxf(ru[k], o);
                ru[k] = fminf(ru[k], o);          // lower keeps min
                xbuf[pa_base + e] = mx;           // partner's result
            }
        }
        __syncthreads();
        if (is_upper) {
            #pragma unroll
            for (int k = 0; k < V; ++k) ru[k] = xbuf[my_base + k];
        }

        // ---- array v ---- (uppers' own-slot read->write is program-ordered)
        if (is_upper) {
            #pragma unroll
            for (int k = 0; k < V; ++k) xbuf[my_base + k] = rv[k];
        }
        __syncthreads();
        if (!is_upper) {
            #pragma unroll
            for (int k = 0; k < V; ++k) {
                const int  e = V - 1 - k;
                const float o  = xbuf[pa_base + e];
                const float mx = fmaxf(rv[k], o);
                rv[k] = fminf(rv[k], o);
                xbuf[pa_base + e] = mx;
            }
        }
        __syncthreads();
        if (is_upper) {
            #pragma unroll
            for (int k = 0; k < V; ++k) rv[k] = xbuf[my_base + k];
        }

        cross_descend<32>(ru, rv, lane);       // strides 1024..32 then reg tail
    }

    // Epilogue: per-thread |diff| sum, wave reduce, block reduce, one atomic.
    float part = 0.f;
    #pragma unroll
    for (int k = 0; k < V; ++k) part += fabsf(ru[k] - rv[k]);

    #pragma unroll
    for (int off = 32; off > 0; off >>= 1)
        part += __shfl_down(part, off, 64);

    const int wid = tid >> 6;
    if (lane == 0) wsum[wid] = part;
    __syncthreads();
    if (tid == 0) {
        float tot = wsum[0] + wsum[1] + wsum[2] + wsum[3];
        atomicAdd(out, tot * scale);
    }
}

extern "C" void kernel_launch(void* const* d_in, const int* in_sizes, int n_in,
                              void* d_out, int out_size, void* d_ws, size_t ws_size,
                              hipStream_t stream)
{
    (void)n_in; (void)out_size; (void)d_ws; (void)ws_size;

    const float* pred = (const float*)d_in[0];
    const float* tru  = (const float*)d_in[1];
    float* out = (float*)d_out;

    const int B = in_sizes[0] / N_ELEM;   // 4096 rows

    hipMemsetAsync(out, 0, sizeof(float), stream);

    const float scale = 1.0f / ((float)N_ELEM * (float)B);
    w1_rows_kernel<<<B / 2, THREADS, 0, stream>>>(pred, tru, out, scale);
}

// Round 4
// 243.700 us; speedup vs baseline: 1.7427x; 1.0396x over previous
//
#include <hip/hip_runtime.h>

// WassersteinLoss: per-row W1 = (1/N) * sum_i |sort(u)[i] - sort(v)[i]|, mean over rows.
// R8: DS-pipe offload + spill revert.
//   R7 post-mortem: bounds=5 still spilled (WRITE_SIZE 29.5 MB vs 64 KB ideal);
//   occupancy 38->44.6% bought nothing (dur 163->164). Across R4/R5/R7 VALUBusy
//   pinned at 68% regardless of occupancy -> per-CU DS pipe (ds_bpermute) is the
//   saturated resource: 15 bperm passes x 64 = 960 DS insts/thread vs ~7.6k VALU.
//   Changes:
//   1) launch_bounds(256,4)  — R5-proven no-spill register budget.
//   2) 6/15 bperm passes -> DPP (exact gfx9 ctrls, bit-identical):
//        mirror X=3  -> quad_perm[3,2,1,0] (0x1B)
//        mirror X=7  -> row_half_mirror    (0x141)
//        mirror X=15 -> row_mirror         (0x140)
//        descend m=8 -> row_ror:8          (0x128)   [x3 passes]
//      ds_bpermute count 960 -> 576 (-40%); +384 VALU movs (+5% on idle headroom).
//   Still bperm: mirrors X=31,63; descends m=4,16,32 (no within-row DPP equiv).
// Carried: ascending-only mirror bitonic, 2-VALU ce2, wave-role-split t^127 LDS
//   exchange (17 KB LDS, conflicts 0).

constexpr int N_ELEM  = 4096;
constexpr int V       = 32;     // elements per thread per array
constexpr int THREADS = 256;    // 4 waves = 2 rows per block

// ---- compare-select: keep min(x,o) if keep_min, else max(x,o).
//      ((o<x) != keep_min) ? x : o  — v_cmp + s_xor_b64 (SALU) + v_cndmask.
__device__ __forceinline__ float ce2(float x, float o, bool keep_min) {
    return ((o < x) != keep_min) ? x : o;
}

// ---- in-register ascending merge of S-blocks: mirror + descend S/4..1 ----
template<int S>
__device__ __forceinline__ void reg_merge(float r[V]) {
    #pragma unroll
    for (int k = 0; k < V; ++k) {
        if ((k & (S >> 1)) == 0) {
            const int j = k ^ (S - 1);          // complement low bits = mirror partner
            const float a = r[k], b = r[j];
            r[k] = fminf(a, b);
            r[j] = fmaxf(a, b);
        }
    }
    #pragma unroll
    for (int s = S >> 2; s >= 1; s >>= 1) {
        #pragma unroll
        for (int k = 0; k < V; ++k) {
            if ((k & s) == 0) {
                const float a = r[k], b = r[k + s];
                r[k]     = fminf(a, b);
                r[k + s] = fmaxf(a, b);
            }
        }
    }
}

// ---- ascending register descend, strides 16..1 (tail of every cross stage) ----
__device__ __forceinline__ void reg_tail_asc(float r[V]) {
    #pragma unroll
    for (int s = 16; s >= 1; s >>= 1) {
        #pragma unroll
        for (int k = 0; k < V; ++k) {
            if ((k & s) == 0) {
                const float a = r[k], b = r[k + s];
                r[k]     = fminf(a, b);
                r[k + s] = fmaxf(a, b);
            }
        }
    }
}

template<int CTRL>
__device__ __forceinline__ float dpp_x(float x) {
    return __int_as_float(__builtin_amdgcn_mov_dpp(__float_as_int(x), CTRL, 0xF, 0xF, true));
}
__device__ __forceinline__ float bperm_x(int pa, float x) {
    return __int_as_float(__builtin_amdgcn_ds_bpermute(pa, __float_as_int(x)));
}

// DPP ctrl for lane partner lane^M (single-bit xor), or -1 if none exists.
//   M=1 -> quad_perm[1,0,3,2]=0xB1; M=2 -> quad_perm[2,3,0,1]=0x4E;
//   M=8 -> row_ror:8=0x128 ((l+8) mod 16 == l^8).
template<int M>
static constexpr int xor_dpp_ctrl() {
    return M == 1 ? 0xB1 : M == 2 ? 0x4E : M == 8 ? 0x128 : -1;
}
// DPP ctrl for mirror partner lane^X (all-ones mask), or -1.
//   X=1 -> 0xB1; X=3 -> quad reverse 0x1B; X=7 -> row_half_mirror 0x141;
//   X=15 -> row_mirror 0x140.
template<int X>
static constexpr int mirror_dpp_ctrl() {
    return X == 1 ? 0xB1 : X == 3 ? 0x1B : X == 7 ? 0x141 : X == 15 ? 0x140 : -1;
}

// ---- descend xor pass, lane partner lane^M, keep_min at (lane&M)==0 ----
template<int M>
__device__ __forceinline__ void xor_pass(float ru[V], float rv[V], int lane) {
    const bool keep_min = (lane & M) == 0;
    constexpr int ctrl = xor_dpp_ctrl<M>();
    if constexpr (ctrl != -1) {
        #pragma unroll
        for (int k = 0; k < V; ++k) {
            ru[k] = ce2(ru[k], dpp_x<ctrl>(ru[k]), keep_min);
            rv[k] = ce2(rv[k], dpp_x<ctrl>(rv[k]), keep_min);
        }
    } else {
        const int pa = (lane ^ M) << 2;
        #pragma unroll
        for (int k = 0; k < V; ++k) {
            ru[k] = ce2(ru[k], bperm_x(pa, ru[k]), keep_min);
            rv[k] = ce2(rv[k], bperm_x(pa, rv[k]), keep_min);
        }
    }
}

// ---- cross descend m=MMAX..1 then register tail (strides 16..1) ----
template<int MMAX>
__device__ __forceinline__ void cross_descend(float ru[V], float rv[V], int lane) {
    if constexpr (MMAX >= 32) xor_pass<32>(ru, rv, lane);
    if constexpr (MMAX >= 16) xor_pass<16>(ru, rv, lane);
    if constexpr (MMAX >= 8)  xor_pass<8>(ru, rv, lane);
    if constexpr (MMAX >= 4)  xor_pass<4>(ru, rv, lane);
    if constexpr (MMAX >= 2)  xor_pass<2>(ru, rv, lane);
    if constexpr (MMAX >= 1)  xor_pass<1>(ru, rv, lane);
    reg_tail_asc(ru);
    reg_tail_asc(rv);
}

// ---- cross mirror pass: (t,k) <-> (t^X, 31-k); keep_min at (t & (X+1)/2)==0.
//      Pairs (k, 31-k) handled jointly so reads precede writes (no hazard). ----
template<int X>
__device__ __forceinline__ void mirror_pass(float ru[V], float rv[V], int lane) {
    const bool keep_min = (lane & ((X + 1) >> 1)) == 0;
    constexpr int ctrl = mirror_dpp_ctrl<X>();
    if constexpr (ctrl != -1) {
        #pragma unroll
        for (int k = 0; k < V / 2; ++k) {
            const int j = V - 1 - k;
            const float ua = dpp_x<ctrl>(ru[j]);
            const float ub = dpp_x<ctrl>(ru[k]);
            ru[k] = ce2(ru[k], ua, keep_min);
            ru[j] = ce2(ru[j], ub, keep_min);
            const float va = dpp_x<ctrl>(rv[j]);
            const float vb = dpp_x<ctrl>(rv[k]);
            rv[k] = ce2(rv[k], va, keep_min);
            rv[j] = ce2(rv[j], vb, keep_min);
        }
    } else {
        const int pa = (lane ^ X) << 2;
        #pragma unroll
        for (int k = 0; k < V / 2; ++k) {
            const int j = V - 1 - k;
            const float ua = bperm_x(pa, ru[j]);
            const float ub = bperm_x(pa, ru[k]);
            ru[k] = ce2(ru[k], ua, keep_min);
            ru[j] = ce2(ru[j], ub, keep_min);
            const float va = bperm_x(pa, rv[j]);
            const float vb = bperm_x(pa, rv[k]);
            rv[k] = ce2(rv[k], va, keep_min);
            rv[j] = ce2(rv[j], vb, keep_min);
        }
    }
}

// ---- full merge stage S (64..2048): cross mirror + cross descend + reg tail ----
template<int S>
__device__ __forceinline__ void stage_m(float ru[V], float rv[V], int lane) {
    mirror_pass<(S >> 5) - 1>(ru, rv, lane);   // X = S/32 - 1  (t-bit mirror mask)
    cross_descend<(S >> 7)>(ru, rv, lane);     // descend strides S/4..32 -> m = S/128..1
}

__global__ __launch_bounds__(THREADS, 4) void w1_rows_kernel(
    const float* __restrict__ pred,
    const float* __restrict__ tru,
    float* __restrict__ out,
    float scale)
{
    // Staging for UPPER threads only (t&64): 128 slots x stride 33 = 16896 B.
    __shared__ float xbuf[128 * 33];
    __shared__ float wsum[THREADS / 64];

    const int tid  = threadIdx.x;
    const int t    = tid & 127;            // thread index within the row (0..127)
    const int lane = tid & 63;
    const int row  = blockIdx.x * 2 + (tid >> 7);
    const size_t base = (size_t)row * N_ELEM + (size_t)t * V;

    // Blocked layout: row-thread t owns global indices [32t, 32t+32).
    float ru[V], rv[V];
    {
        const float4* u4 = (const float4*)(pred + base);
        const float4* v4 = (const float4*)(tru  + base);
        #pragma unroll
        for (int c = 0; c < V / 4; ++c) {
            float4 a = u4[c], b = v4[c];
            ru[4*c+0] = a.x; ru[4*c+1] = a.y; ru[4*c+2] = a.z; ru[4*c+3] = a.w;
            rv[4*c+0] = b.x; rv[4*c+1] = b.y; rv[4*c+2] = b.z; rv[4*c+3] = b.w;
        }
    }

    // Stages S=2..32: fully in-register ascending sort of each 32-run.
    reg_merge<2>(ru);  reg_merge<2>(rv);
    reg_merge<4>(ru);  reg_merge<4>(rv);
    reg_merge<8>(ru);  reg_merge<8>(rv);
    reg_merge<16>(ru); reg_merge<16>(rv);
    reg_merge<32>(ru); reg_merge<32>(rv);

    // Stages S=64..2048: cross-lane mirror + descend, everything ascending.
    stage_m<64>(ru, rv, lane);
    stage_m<128>(ru, rv, lane);
    stage_m<256>(ru, rv, lane);
    stage_m<512>(ru, rv, lane);
    stage_m<1024>(ru, rv, lane);
    stage_m<2048>(ru, rv, lane);

    // Stage S=4096: mirror pass g <-> g^4095, i.e. (t,k) <-> (t^127, 31-k).
    // Wave-role split: uppers (t&64, waves 1&3 of the block) stage all 32 regs;
    // lowers read partner value reversed (slot 63-lane, elem 31-k), keep min,
    // write max back; uppers re-read. Whole-wave-uniform branches.
    {
        const bool is_upper = (t & 64) != 0;
        const int  slot_row = (tid >> 7) * 64;
        const int  my_base  = (slot_row + lane) * 33;        // uppers' own slot
        const int  pa_base  = (slot_row + (63 - lane)) * 33; // lowers' partner slot

        // ---- array u ----
        if (is_upper) {
            #pragma unroll
            for (int k = 0; k < V; ++k) xbuf[my_base + k] = ru[k];
        }
        __syncthreads();
        if (!is_upper) {
            #pragma unroll
            for (int k = 0; k < V; ++k) {
                const int  e = V - 1 - k;
                const float o  = xbuf[pa_base + e];
                const float mx = fmaxf(ru[k], o);
                ru[k] = fminf(ru[k], o);          // lower keeps min
                xbuf[pa_base + e] = mx;           // partner's result
            }
        }
        __syncthreads();
        if (is_upper) {
            #pragma unroll
            for (int k = 0; k < V; ++k) ru[k] = xbuf[my_base + k];
        }

        // ---- array v ---- (uppers' own-slot read->write is program-ordered)
        if (is_upper) {
            #pragma unroll
            for (int k = 0; k < V; ++k) xbuf[my_base + k] = rv[k];
        }
        __syncthreads();
        if (!is_upper) {
            #pragma unroll
            for (int k = 0; k < V; ++k) {
                const int  e = V - 1 - k;
                const float o  = xbuf[pa_base + e];
                const float mx = fmaxf(rv[k], o);
                rv[k] = fminf(rv[k], o);
                xbuf[pa_base + e] = mx;
            }
        }
        __syncthreads();
        if (is_upper) {
            #pragma unroll
            for (int k = 0; k < V; ++k) rv[k] = xbuf[my_base + k];
        }

        cross_descend<32>(ru, rv, lane);       // strides 1024..32 then reg tail
    }

    // Epilogue: per-thread |diff| sum, wave reduce, block reduce, one atomic.
    float part = 0.f;
    #pragma unroll
    for (int k = 0; k < V; ++k) part += fabsf(ru[k] - rv[k]);

    #pragma unroll
    for (int off = 32; off > 0; off >>= 1)
        part += __shfl_down(part, off, 64);

    const int wid = tid >> 6;
    if (lane == 0) wsum[wid] = part;
    __syncthreads();
    if (tid == 0) {
        float tot = wsum[0] + wsum[1] + wsum[2] + wsum[3];
        atomicAdd(out, tot * scale);
    }
}

extern "C" void kernel_launch(void* const* d_in, const int* in_sizes, int n_in,
                              void* d_out, int out_size, void* d_ws, size_t ws_size,
                              hipStream_t stream)
{
    (void)n_in; (void)out_size; (void)d_ws; (void)ws_size;

    const float* pred = (const float*)d_in[0];
    const float* tru  = (const float*)d_in[1];
    float* out = (float*)d_out;

    const int B = in_sizes[0] / N_ELEM;   // 4096 rows

    hipMemsetAsync(out, 0, sizeof(float), stream);

    const float scale = 1.0f / ((float)N_ELEM * (float)B);
    w1_rows_kernel<<<B / 2, THREADS, 0, stream>>>(pred, tru, out, scale);
}